// Round 20
// baseline (57.580 us; speedup 1.0000x reference)
//
#include <hip/hip_runtime.h>

#define H_IMG 128
#define W_IMG 48
#define CIN   64
#define DM    32
#define NH    8
#define NPIX  6144
#define WPAD  50
#define HPAD  130

// 0.5 (dh^-0.5) * log2(e): folded into wq/bq at load time
#define Q_SCALE 0.7213475204444817f

typedef _Float16 half4 __attribute__((ext_vector_type(4)));
typedef __fp16   fp16x2 __attribute__((ext_vector_type(2)));
typedef float    f32x4 __attribute__((ext_vector_type(4)));

__device__ __forceinline__ float fexp2(float x) { return __builtin_amdgcn_exp2f(x); }

// exp2 the 4 logits, pack to f16 via two cvt_pkrtz dwords (bitcast, no shuffles)
__device__ __forceinline__ half4 exp_pack(f32x4 s) {
    union { fp16x2 h2[2]; half4 h4; } u;
    u.h2[0] = __builtin_amdgcn_cvt_pkrtz(fexp2(s[0]), fexp2(s[1]));
    u.h2[1] = __builtin_amdgcn_cvt_pkrtz(fexp2(s[2]), fexp2(s[3]));
    return u.h4;
}

// ---------------------------------------------------------------------------
// K1: QKV conv as MFMA GEMM, dy-split, DIRECT x/w loads (validated R17).
// ---------------------------------------------------------------------------
__global__ __launch_bounds__(192) void qkv_mfma_kernel(
    const float* __restrict__ x,
    const float* __restrict__ wq, const float* __restrict__ bq,
    const float* __restrict__ wk, const float* __restrict__ bk,
    const float* __restrict__ wv, const float* __restrict__ bv,
    half4* __restrict__ qhi, half4* __restrict__ qlo,
    half4* __restrict__ khi, half4* __restrict__ klo,
    _Float16* __restrict__ vT)
{
    __shared__ f32x4 redq[2][64];
    __shared__ _Float16 lt[2][16][20];

    const int pt  = blockIdx.x % 384;
    const int ntm = blockIdx.x / 384;
    const int nt  = ntm % 2;
    const int m   = ntm / 2;
    const int wav = __builtin_amdgcn_readfirstlane(threadIdx.x >> 6);  // = dy
    const int lane = threadIdx.x & 63;
    const int r    = lane & 15;
    const int g16  = lane >> 4;

    const int y   = pt / 3;                 // wave-uniform image row
    const int x0c = (pt % 3) * 16 + r;      // pixel column (per lane)
    const int yy  = y + wav - 1;
    const bool vrow = (yy >= 0) && (yy < H_IMG);

    const int ch = nt * 16 + r;
    const float* w = (m == 0) ? wq : (m == 1) ? wk : wv;
    const float  s = (m == 0) ? Q_SCALE : 1.0f;

    f32x4 acc[4] = {{0.f,0.f,0.f,0.f},{0.f,0.f,0.f,0.f},
                    {0.f,0.f,0.f,0.f},{0.f,0.f,0.f,0.f}};

    #pragma unroll
    for (int dx = 0; dx < 3; ++dx) {
        const int xx = x0c + dx - 1;
        const bool v = vrow && (xx >= 0) && (xx < W_IMG);
        const int poff = v ? (yy * W_IMG + xx) : 0;     // clamped when masked
        const float* xsrc = x + (size_t)poff * CIN + 4 * g16;
        const float* wp0  = w + (size_t)(wav * 3 + dx) * CIN * DM + 4 * g16 * DM + ch;
        #pragma unroll
        for (int cb = 0; cb < 4; ++cb) {
            f32x4 xv = {0.f, 0.f, 0.f, 0.f};
            if (v) xv = *reinterpret_cast<const f32x4*>(xsrc + cb * 16);
            half4 xa = { (_Float16)xv[0], (_Float16)xv[1],
                         (_Float16)xv[2], (_Float16)xv[3] };
            const float* wp = wp0 + cb * 16 * DM;
            half4 wf = { (_Float16)(wp[0 * DM] * s), (_Float16)(wp[1 * DM] * s),
                         (_Float16)(wp[2 * DM] * s), (_Float16)(wp[3 * DM] * s) };
            acc[cb] = __builtin_amdgcn_mfma_f32_16x16x16f16(xa, wf, acc[cb], 0, 0, 0);
        }
    }

    f32x4 o = (acc[0] + acc[1]) + (acc[2] + acc[3]);

    if (wav > 0) redq[wav - 1][lane] = o;
    __syncthreads();
    if (wav != 0) {
        if (wav == 1 && m == 2) {           // ones plane for (pt, nt)
            const int pix = pt * 16 + (lane & 15);
            const int h   = nt * 4 + (lane >> 4);
            vT[(size_t)(h * 5 + 4) * NPIX + pix] = (_Float16)1.0f;
        }
        return;
    }

    o += redq[0][lane] + redq[1][lane];

    const float* b = (m == 0) ? bq : (m == 1) ? bk : bv;
    const float bias = b[ch] * s;
    #pragma unroll
    for (int j = 0; j < 4; ++j) o[j] += bias;

    if (m == 2) {
        const int plane = (ch >> 2) * 5 + (ch & 3);
        const int pix0 = pt * 16 + 4 * g16;
        half4 hv = { (_Float16)o[0], (_Float16)o[1], (_Float16)o[2], (_Float16)o[3] };
        *reinterpret_cast<half4*>(vT + (size_t)plane * NPIX + pix0) = hv;
    } else {
        #pragma unroll
        for (int j = 0; j < 4; ++j) {
            const float val = o[j];
            const _Float16 hi = (_Float16)val;
            const _Float16 lo = (_Float16)(val - (float)hi);
            lt[0][4 * g16 + j][r] = hi;
            lt[1][4 * g16 + j][r] = lo;
        }
        const int p4 = lane & 15;              // pixel within tile
        const int hh = lane >> 4;              // head within nt-half
        const half4 hv = *reinterpret_cast<const half4*>(&lt[0][p4][hh * 4]);
        const half4 lv = *reinterpret_cast<const half4*>(&lt[1][p4][hh * 4]);
        const int h = nt * 4 + hh;
        const size_t idx = (size_t)h * NPIX + pt * 16 + p4;
        ((half4*)((m == 0) ? qhi : khi))[idx] = hv;
        ((half4*)((m == 0) ? qlo : klo))[idx] = lv;
    }
}

// ---------------------------------------------------------------------------
// K2: fused MFMA local attention + split-K reduce + normalize, SSEG=4,
// 8 waves/block (validated R19 geometry) + 2-iteration-deep software
// pipeline: loads for row r+2 issued before row r's compute; 12 staging
// VGPRs held in named variables (no register cap — 512-thr block has VGPR
// headroom).  Last-iteration over-reads land inside d_ws (vT/attpad),
// values unused.  hg==0 blocks zero the attpad border at kernel start.
// ---------------------------------------------------------------------------
__global__ __launch_bounds__(512) void attn_mfma_kernel(
    const half4* __restrict__ qhi, const half4* __restrict__ qlo,
    const half4* __restrict__ khi, const half4* __restrict__ klo,
    const _Float16* __restrict__ vT,
    _Float16* __restrict__ attpad)
{
    __shared__ f32x4 red[8][2][64];    // 16 KB

    const int hg  = blockIdx.x / 48;
    const int qq  = blockIdx.x % 48;
    const int h   = hg >> 1, g = hg & 1;
    const int wav = __builtin_amdgcn_readfirstlane(threadIdx.x >> 6);  // 0..7
    const int seg = wav >> 1;
    const int u   = wav & 1;
    const int qt0 = qq * 4 + u * 2;           // tiles qt0, qt0+1
    const int lane = threadIdx.x & 63;
    const int c    = lane & 15;
    const int g16  = lane >> 4;
    const int c0   = g * 16;

    if (hg == 0 && wav == 0) {                // border zero (356 pad pixels)
        const int i = qq * 8 + (lane >> 3);
        if (i < 356) {
            int py, px;
            if (i < 50)       { py = 0;              px = i; }
            else if (i < 100) { py = HPAD - 1;       px = i - 50; }
            else if (i < 228) { py = 1 + (i - 100);  px = 0; }
            else              { py = 1 + (i - 228);  px = WPAD - 1; }
            const half4 z = {};
            *reinterpret_cast<half4*>(
                attpad + ((size_t)py * WPAD + px) * DM + (lane & 7) * 4) = z;
        }
    }

    half4 qfA = {}, qfB = {};
    {
        const half4* qsrc = (g16 == 1) ? qlo : qhi;
        const int qa  = qt0 * 16 + c;
        const int qay = qa / 24;
        const int qb  = qa + 16;
        const int qby = qb / 24;
        if (g16 < 3) {
            qfA = qsrc[h * NPIX + qay * W_IMG + g * 24 + (qa - qay * 24)];
            qfB = qsrc[h * NPIX + qby * W_IMG + g * 24 + (qb - qby * 24)];
        }
    }

    const half4* kb = ((g16 == 2) ? klo : khi) + h * NPIX + c;
    const int vplane = (c < 4) ? c : 4;
    const _Float16* vb = vT + (h * 5 + vplane) * NPIX + 4 * g16;

    const f32x4 zc = {0.f, 0.f, 0.f, 0.f};
    f32x4 oA0 = zc, oA1 = zc, oB0 = zc, oB1 = zc;

    // ---- 2-deep pipeline: stage rows r0, r0+1 ----
    int koffA = (seg * 32) * W_IMG + c0;
    int koffB = koffA + W_IMG;
    half4 k0a = kb[koffA], k1a = kb[koffA + 16];
    half4 v0a = *reinterpret_cast<const half4*>(vb + koffA);
    half4 v1a = *reinterpret_cast<const half4*>(vb + koffA + 16);
    half4 k0b = kb[koffB], k1b = kb[koffB + 16];
    half4 v0b = *reinterpret_cast<const half4*>(vb + koffB);
    half4 v1b = *reinterpret_cast<const half4*>(vb + koffB + 16);

    #pragma unroll 4
    for (int r = 0; r < 32; ++r) {
        // issue loads for row r+2 (last 2 iters over-read into ws — unused)
        const int koffC = koffB + W_IMG;
        const half4 nk0 = kb[koffC];
        const half4 nk1 = kb[koffC + 16];
        const half4 nv0 = *reinterpret_cast<const half4*>(vb + koffC);
        const half4 nv1 = *reinterpret_cast<const half4*>(vb + koffC + 16);

        // compute with stage A
        const f32x4 sA0 = __builtin_amdgcn_mfma_f32_16x16x16f16(k0a, qfA, zc, 0, 0, 0);
        const f32x4 sA1 = __builtin_amdgcn_mfma_f32_16x16x16f16(k1a, qfA, zc, 0, 0, 0);
        const f32x4 sB0 = __builtin_amdgcn_mfma_f32_16x16x16f16(k0a, qfB, zc, 0, 0, 0);
        const f32x4 sB1 = __builtin_amdgcn_mfma_f32_16x16x16f16(k1a, qfB, zc, 0, 0, 0);

        const half4 pA0 = exp_pack(sA0);
        const half4 pA1 = exp_pack(sA1);
        const half4 pB0 = exp_pack(sB0);
        const half4 pB1 = exp_pack(sB1);

        oA0 = __builtin_amdgcn_mfma_f32_16x16x16f16(pA0, v0a, oA0, 0, 0, 0);
        oA1 = __builtin_amdgcn_mfma_f32_16x16x16f16(pA1, v1a, oA1, 0, 0, 0);
        oB0 = __builtin_amdgcn_mfma_f32_16x16x16f16(pB0, v0a, oB0, 0, 0, 0);
        oB1 = __builtin_amdgcn_mfma_f32_16x16x16f16(pB1, v1a, oB1, 0, 0, 0);

        // rotate stages (named registers — compile-time indices)
        k0a = k0b; k1a = k1b; v0a = v0b; v1a = v1b;
        k0b = nk0; k1b = nk1; v0b = nv0; v1b = nv1;
        koffA = koffB; koffB = koffC;
    }

    red[wav][0][lane] = oA0 + oA1;
    red[wav][1][lane] = oB0 + oB1;
    __syncthreads();

    if (seg < 2) {
        const int t = seg;                     // tile within pair
        f32x4 o = red[u][t][lane];
        o += red[2 + u][t][lane];
        o += red[4 + u][t][lane];
        o += red[6 + u][t][lane];

        const int baddr = (g16 * 16 + 4) << 2; // ssum column lane, in bytes
        f32x4 on;
        #pragma unroll
        for (int r = 0; r < 4; ++r) {
            const float ss = __int_as_float(
                __builtin_amdgcn_ds_bpermute(baddr, __float_as_int(o[r])));
            on[r] = o[r] * __builtin_amdgcn_rcpf(ss);
        }

        if (c < 4) {
            const int qt = qt0 + t;
            #pragma unroll
            for (int r = 0; r < 4; ++r) {
                const int q  = qt * 16 + 4 * g16 + r;
                const int qy = q / 24;
                const int qx = g * 24 + (q - qy * 24);
                attpad[((size_t)(qy + 1) * WPAD + qx + 1) * DM + h * 4 + c] =
                    (_Float16)on[r];
            }
        }
    }
}

// ---------------------------------------------------------------------------
// K3: output conv as MFMA GEMM, dy-split, DIRECT wo loads (validated R17).
// ---------------------------------------------------------------------------
__global__ __launch_bounds__(192) void out_mfma_kernel(
    const _Float16* __restrict__ attpad,
    const float* __restrict__ wo,
    float* __restrict__ out)
{
    __shared__ f32x4 redo[2][64];

    const int pt  = blockIdx.x % 384;
    const int nt  = blockIdx.x / 384;        // 0..3
    const int wav = __builtin_amdgcn_readfirstlane(threadIdx.x >> 6);  // = dy
    const int lane = threadIdx.x & 63;
    const int r    = lane & 15;
    const int g16  = lane >> 4;

    const int y   = pt / 3;
    const int x0  = (pt % 3) * 16 + r;
    const _Float16* ab = attpad + ((size_t)y * WPAD + x0) * DM + 4 * g16;

    const int ch = nt * 16 + r;

    f32x4 a0 = {0.f, 0.f, 0.f, 0.f}, a1 = {0.f, 0.f, 0.f, 0.f};

    #pragma unroll
    for (int dx = 0; dx < 3; ++dx) {
        const int toff = (wav * WPAD + dx) * DM;
        const float* wp0 = wo + (size_t)(wav * 3 + dx) * DM * 64 + 4 * g16 * 64 + ch;
        #pragma unroll
        for (int cb = 0; cb < 2; ++cb) {
            const half4 xa = *reinterpret_cast<const half4*>(ab + toff + cb * 16);
            const float* wp = wp0 + cb * 16 * 64;
            half4 wf = { (_Float16)wp[0 * 64], (_Float16)wp[1 * 64],
                         (_Float16)wp[2 * 64], (_Float16)wp[3 * 64] };
            if (cb & 1)
                a1 = __builtin_amdgcn_mfma_f32_16x16x16f16(xa, wf, a1, 0, 0, 0);
            else
                a0 = __builtin_amdgcn_mfma_f32_16x16x16f16(xa, wf, a0, 0, 0, 0);
        }
    }

    f32x4 o = a0 + a1;
    if (wav > 0) redo[wav - 1][lane] = o;
    __syncthreads();
    if (wav != 0) return;

    o += redo[0][lane] + redo[1][lane];

    const int pix0 = pt * 16 + 4 * g16;
    #pragma unroll
    for (int j = 0; j < 4; ++j)
        out[(size_t)(pix0 + j) * 64 + nt * 16 + r] = o[j];
}

// ---------------------------------------------------------------------------
extern "C" void kernel_launch(void* const* d_in, const int* in_sizes, int n_in,
                              void* d_out, int out_size, void* d_ws, size_t ws_size,
                              hipStream_t stream)
{
    const float* x  = (const float*)d_in[0];
    const float* wq = (const float*)d_in[1];
    const float* bq = (const float*)d_in[2];
    const float* wk = (const float*)d_in[3];
    const float* bk = (const float*)d_in[4];
    const float* wv = (const float*)d_in[5];
    const float* bv = (const float*)d_in[6];
    const float* wo = (const float*)d_in[7];
    float* out = (float*)d_out;

    // workspace layout (bytes)
    char* base = (char*)d_ws;
    half4*    qhi    = (half4*)(base + 0);          //  393216
    half4*    qlo    = (half4*)(base + 393216);
    half4*    khi    = (half4*)(base + 786432);
    half4*    klo    = (half4*)(base + 1179648);
    _Float16* vT     = (_Float16*)(base + 1572864); //  491520 (8h x 5 planes)
    _Float16* attpad = (_Float16*)(base + 2064384); //  416000 -> 2480384

    hipLaunchKernelGGL(qkv_mfma_kernel, dim3(2304), dim3(192), 0, stream,
                       x, wq, bq, wk, bk, wv, bv, qhi, qlo, khi, klo, vT);

    hipLaunchKernelGGL(attn_mfma_kernel, dim3(16 * 48), dim3(512), 0, stream,
                       qhi, qlo, khi, klo, vT, attpad);

    hipLaunchKernelGGL(out_mfma_kernel, dim3(4 * 384), dim3(192), 0, stream,
                       attpad, wo, out);
}

// Round 21
// 57.013 us; speedup vs baseline: 1.0099x; 1.0099x over previous
//
#include <hip/hip_runtime.h>

#define H_IMG 128
#define W_IMG 48
#define CIN   64
#define DM    32
#define NH    8
#define NPIX  6144
#define WPAD  50
#define HPAD  130

// 0.5 (dh^-0.5) * log2(e): folded into wq/bq at load time
#define Q_SCALE 0.7213475204444817f

typedef _Float16 half4 __attribute__((ext_vector_type(4)));
typedef __fp16   fp16x2 __attribute__((ext_vector_type(2)));
typedef float    f32x4 __attribute__((ext_vector_type(4)));

__device__ __forceinline__ float fexp2(float x) { return __builtin_amdgcn_exp2f(x); }

// exp2 the 4 logits, pack to f16 via two cvt_pkrtz dwords (bitcast, no shuffles)
__device__ __forceinline__ half4 exp_pack(f32x4 s) {
    union { fp16x2 h2[2]; half4 h4; } u;
    u.h2[0] = __builtin_amdgcn_cvt_pkrtz(fexp2(s[0]), fexp2(s[1]));
    u.h2[1] = __builtin_amdgcn_cvt_pkrtz(fexp2(s[2]), fexp2(s[3]));
    return u.h4;
}

// ---------------------------------------------------------------------------
// K1: QKV conv as MFMA GEMM, dy-split, LDS-staged weights, 2 pixel tiles
// per block.  grid = 6(ntm) x 192(ptp); block = 384 thr = 6 waves:
// wav = up*3 + dyw; up = pt half (pt = ptp*2+up), dyw = dy.
// Staging (waves 0-2 only): lw[dyw][dx][ch][ci] = f16(w[tap][ci][nt*16+ch]*s)
// via 12 coalesced float4 loads per wave; rows padded to 68 halves (2-way
// max bank aliasing on the b64 fragment reads).  Fragment values are
// bit-identical to R17's direct gather loads.
// ---------------------------------------------------------------------------
__global__ __launch_bounds__(384) void qkv_mfma_kernel(
    const float* __restrict__ x,
    const float* __restrict__ wq, const float* __restrict__ bq,
    const float* __restrict__ wk, const float* __restrict__ bk,
    const float* __restrict__ wv, const float* __restrict__ bv,
    half4* __restrict__ qhi, half4* __restrict__ qlo,
    half4* __restrict__ khi, half4* __restrict__ klo,
    _Float16* __restrict__ vT)
{
    __shared__ __align__(16) _Float16 lw[3][3][16][68];   // 19584 B
    __shared__ f32x4 redq[2][2][64];                      //  4096 B
    __shared__ _Float16 lt[2][2][16][20];                 //  2560 B

    const int ptp = blockIdx.x % 192;
    const int ntm = blockIdx.x / 192;
    const int nt  = ntm % 2;
    const int m   = ntm / 2;
    const int wav = __builtin_amdgcn_readfirstlane(threadIdx.x >> 6);  // 0..5
    const int up  = __builtin_amdgcn_readfirstlane(wav / 3);
    const int dyw = __builtin_amdgcn_readfirstlane(wav % 3);
    const int pt  = ptp * 2 + up;
    const int lane = threadIdx.x & 63;
    const int r    = lane & 15;
    const int g16  = lane >> 4;

    const float* w = (m == 0) ? wq : (m == 1) ? wk : wv;
    const float  s = (m == 0) ? Q_SCALE : 1.0f;

    // ---- stage weights (waves 0-2; wave dyw stages lw[dyw]) ----
    if (wav < 3) {
        const int ci_l = lane >> 2;          // 0..15
        const int chq  = lane & 3;           // 0..3
        #pragma unroll
        for (int dx = 0; dx < 3; ++dx) {
            #pragma unroll
            for (int cib = 0; cib < 4; ++cib) {
                const int ci = cib * 16 + ci_l;
                const f32x4 wv4 = *reinterpret_cast<const f32x4*>(
                    w + (size_t)(wav * 3 + dx) * CIN * DM + (size_t)ci * DM
                      + nt * 16 + 4 * chq);
                #pragma unroll
                for (int e = 0; e < 4; ++e)
                    lw[wav][dx][4 * chq + e][ci] = (_Float16)(wv4[e] * s);
            }
        }
    }
    __syncthreads();

    const int y   = pt / 3;                 // wave-uniform image row
    const int x0c = (pt % 3) * 16 + r;      // pixel column (per lane)
    const int yy  = y + dyw - 1;
    const bool vrow = (yy >= 0) && (yy < H_IMG);
    const int ch = nt * 16 + r;

    f32x4 acc[4] = {{0.f,0.f,0.f,0.f},{0.f,0.f,0.f,0.f},
                    {0.f,0.f,0.f,0.f},{0.f,0.f,0.f,0.f}};

    #pragma unroll
    for (int dx = 0; dx < 3; ++dx) {
        const int xx = x0c + dx - 1;
        const bool v = vrow && (xx >= 0) && (xx < W_IMG);
        const int poff = v ? (yy * W_IMG + xx) : 0;     // clamped when masked
        const float* xsrc = x + (size_t)poff * CIN + 4 * g16;
        #pragma unroll
        for (int cb = 0; cb < 4; ++cb) {
            f32x4 xv = {0.f, 0.f, 0.f, 0.f};
            if (v) xv = *reinterpret_cast<const f32x4*>(xsrc + cb * 16);
            half4 xa = { (_Float16)xv[0], (_Float16)xv[1],
                         (_Float16)xv[2], (_Float16)xv[3] };
            const half4 wf = *reinterpret_cast<const half4*>(
                &lw[dyw][dx][r][cb * 16 + 4 * g16]);
            acc[cb] = __builtin_amdgcn_mfma_f32_16x16x16f16(xa, wf, acc[cb], 0, 0, 0);
        }
    }

    f32x4 o = (acc[0] + acc[1]) + (acc[2] + acc[3]);

    if (dyw > 0) redq[up][dyw - 1][lane] = o;
    __syncthreads();
    if (dyw != 0) {
        if (dyw == 1 && m == 2) {           // ones plane for (pt, nt)
            const int pix = pt * 16 + (lane & 15);
            const int h   = nt * 4 + (lane >> 4);
            vT[(size_t)(h * 5 + 4) * NPIX + pix] = (_Float16)1.0f;
        }
        return;
    }

    o += redq[up][0][lane] + redq[up][1][lane];

    const float* b = (m == 0) ? bq : (m == 1) ? bk : bv;
    const float bias = b[ch] * s;
    #pragma unroll
    for (int j = 0; j < 4; ++j) o[j] += bias;

    if (m == 2) {
        const int plane = (ch >> 2) * 5 + (ch & 3);
        const int pix0 = pt * 16 + 4 * g16;
        half4 hv = { (_Float16)o[0], (_Float16)o[1], (_Float16)o[2], (_Float16)o[3] };
        *reinterpret_cast<half4*>(vT + (size_t)plane * NPIX + pix0) = hv;
    } else {
        #pragma unroll
        for (int j = 0; j < 4; ++j) {
            const float val = o[j];
            const _Float16 hi = (_Float16)val;
            const _Float16 lo = (_Float16)(val - (float)hi);
            lt[up][0][4 * g16 + j][r] = hi;
            lt[up][1][4 * g16 + j][r] = lo;
        }
        const int p4 = lane & 15;              // pixel within tile
        const int hh = lane >> 4;              // head within nt-half
        const half4 hv = *reinterpret_cast<const half4*>(&lt[up][0][p4][hh * 4]);
        const half4 lv = *reinterpret_cast<const half4*>(&lt[up][1][p4][hh * 4]);
        const int h = nt * 4 + hh;
        const size_t idx = (size_t)h * NPIX + pt * 16 + p4;
        ((half4*)((m == 0) ? qhi : khi))[idx] = hv;
        ((half4*)((m == 0) ? qlo : klo))[idx] = lv;
    }
}

// ---------------------------------------------------------------------------
// K2: fused MFMA local attention + split-K reduce + normalize, SSEG=4,
// 8 waves/block (validated R19 measured-equal-best geometry).
// hg==0 blocks zero the attpad border at kernel start.
// ---------------------------------------------------------------------------
__global__ __launch_bounds__(512) void attn_mfma_kernel(
    const half4* __restrict__ qhi, const half4* __restrict__ qlo,
    const half4* __restrict__ khi, const half4* __restrict__ klo,
    const _Float16* __restrict__ vT,
    _Float16* __restrict__ attpad)
{
    __shared__ f32x4 red[8][2][64];    // 16 KB

    const int hg  = blockIdx.x / 48;
    const int qq  = blockIdx.x % 48;
    const int h   = hg >> 1, g = hg & 1;
    const int wav = __builtin_amdgcn_readfirstlane(threadIdx.x >> 6);  // 0..7
    const int seg = wav >> 1;
    const int u   = wav & 1;
    const int qt0 = qq * 4 + u * 2;           // tiles qt0, qt0+1
    const int lane = threadIdx.x & 63;
    const int c    = lane & 15;
    const int g16  = lane >> 4;
    const int c0   = g * 16;

    if (hg == 0 && wav == 0) {                // border zero (356 pad pixels)
        const int i = qq * 8 + (lane >> 3);
        if (i < 356) {
            int py, px;
            if (i < 50)       { py = 0;              px = i; }
            else if (i < 100) { py = HPAD - 1;       px = i - 50; }
            else if (i < 228) { py = 1 + (i - 100);  px = 0; }
            else              { py = 1 + (i - 228);  px = WPAD - 1; }
            const half4 z = {};
            *reinterpret_cast<half4*>(
                attpad + ((size_t)py * WPAD + px) * DM + (lane & 7) * 4) = z;
        }
    }

    half4 qfA = {}, qfB = {};
    {
        const half4* qsrc = (g16 == 1) ? qlo : qhi;
        const int qa  = qt0 * 16 + c;
        const int qay = qa / 24;
        const int qb  = qa + 16;
        const int qby = qb / 24;
        if (g16 < 3) {
            qfA = qsrc[h * NPIX + qay * W_IMG + g * 24 + (qa - qay * 24)];
            qfB = qsrc[h * NPIX + qby * W_IMG + g * 24 + (qb - qby * 24)];
        }
    }

    const half4* kb = ((g16 == 2) ? klo : khi) + h * NPIX + c;
    const int vplane = (c < 4) ? c : 4;
    const _Float16* vb = vT + (h * 5 + vplane) * NPIX + 4 * g16;

    const f32x4 zc = {0.f, 0.f, 0.f, 0.f};
    f32x4 oA0 = zc, oA1 = zc, oB0 = zc, oB1 = zc;

    const int r0 = seg * 32;
    #pragma unroll 4
    for (int r = 0; r < 32; ++r) {
        const int koff = (r0 + r) * W_IMG + c0;

        const half4 k0 = kb[koff];
        const half4 k1 = kb[koff + 16];
        const half4 v0 = *reinterpret_cast<const half4*>(vb + koff);
        const half4 v1 = *reinterpret_cast<const half4*>(vb + koff + 16);

        const f32x4 sA0 = __builtin_amdgcn_mfma_f32_16x16x16f16(k0, qfA, zc, 0, 0, 0);
        const f32x4 sA1 = __builtin_amdgcn_mfma_f32_16x16x16f16(k1, qfA, zc, 0, 0, 0);
        const f32x4 sB0 = __builtin_amdgcn_mfma_f32_16x16x16f16(k0, qfB, zc, 0, 0, 0);
        const f32x4 sB1 = __builtin_amdgcn_mfma_f32_16x16x16f16(k1, qfB, zc, 0, 0, 0);

        const half4 pA0 = exp_pack(sA0);
        const half4 pA1 = exp_pack(sA1);
        const half4 pB0 = exp_pack(sB0);
        const half4 pB1 = exp_pack(sB1);

        oA0 = __builtin_amdgcn_mfma_f32_16x16x16f16(pA0, v0, oA0, 0, 0, 0);
        oA1 = __builtin_amdgcn_mfma_f32_16x16x16f16(pA1, v1, oA1, 0, 0, 0);
        oB0 = __builtin_amdgcn_mfma_f32_16x16x16f16(pB0, v0, oB0, 0, 0, 0);
        oB1 = __builtin_amdgcn_mfma_f32_16x16x16f16(pB1, v1, oB1, 0, 0, 0);
    }

    red[wav][0][lane] = oA0 + oA1;
    red[wav][1][lane] = oB0 + oB1;
    __syncthreads();

    if (seg < 2) {
        const int t = seg;                     // tile within pair
        f32x4 o = red[u][t][lane];
        o += red[2 + u][t][lane];
        o += red[4 + u][t][lane];
        o += red[6 + u][t][lane];

        const int baddr = (g16 * 16 + 4) << 2; // ssum column lane, in bytes
        f32x4 on;
        #pragma unroll
        for (int r = 0; r < 4; ++r) {
            const float ss = __int_as_float(
                __builtin_amdgcn_ds_bpermute(baddr, __float_as_int(o[r])));
            on[r] = o[r] * __builtin_amdgcn_rcpf(ss);
        }

        if (c < 4) {
            const int qt = qt0 + t;
            #pragma unroll
            for (int r = 0; r < 4; ++r) {
                const int q  = qt * 16 + 4 * g16 + r;
                const int qy = q / 24;
                const int qx = g * 24 + (q - qy * 24);
                attpad[((size_t)(qy + 1) * WPAD + qx + 1) * DM + h * 4 + c] =
                    (_Float16)on[r];
            }
        }
    }
}

// ---------------------------------------------------------------------------
// K3: output conv as MFMA GEMM, dy-split, DIRECT wo loads (validated R17).
// ---------------------------------------------------------------------------
__global__ __launch_bounds__(192) void out_mfma_kernel(
    const _Float16* __restrict__ attpad,
    const float* __restrict__ wo,
    float* __restrict__ out)
{
    __shared__ f32x4 redo[2][64];

    const int pt  = blockIdx.x % 384;
    const int nt  = blockIdx.x / 384;        // 0..3
    const int wav = __builtin_amdgcn_readfirstlane(threadIdx.x >> 6);  // = dy
    const int lane = threadIdx.x & 63;
    const int r    = lane & 15;
    const int g16  = lane >> 4;

    const int y   = pt / 3;
    const int x0  = (pt % 3) * 16 + r;
    const _Float16* ab = attpad + ((size_t)y * WPAD + x0) * DM + 4 * g16;

    const int ch = nt * 16 + r;

    f32x4 a0 = {0.f, 0.f, 0.f, 0.f}, a1 = {0.f, 0.f, 0.f, 0.f};

    #pragma unroll
    for (int dx = 0; dx < 3; ++dx) {
        const int toff = (wav * WPAD + dx) * DM;
        const float* wp0 = wo + (size_t)(wav * 3 + dx) * DM * 64 + 4 * g16 * 64 + ch;
        #pragma unroll
        for (int cb = 0; cb < 2; ++cb) {
            const half4 xa = *reinterpret_cast<const half4*>(ab + toff + cb * 16);
            const float* wp = wp0 + cb * 16 * 64;
            half4 wf = { (_Float16)wp[0 * 64], (_Float16)wp[1 * 64],
                         (_Float16)wp[2 * 64], (_Float16)wp[3 * 64] };
            if (cb & 1)
                a1 = __builtin_amdgcn_mfma_f32_16x16x16f16(xa, wf, a1, 0, 0, 0);
            else
                a0 = __builtin_amdgcn_mfma_f32_16x16x16f16(xa, wf, a0, 0, 0, 0);
        }
    }

    f32x4 o = a0 + a1;
    if (wav > 0) redo[wav - 1][lane] = o;
    __syncthreads();
    if (wav != 0) return;

    o += redo[0][lane] + redo[1][lane];

    const int pix0 = pt * 16 + 4 * g16;
    #pragma unroll
    for (int j = 0; j < 4; ++j)
        out[(size_t)(pix0 + j) * 64 + nt * 16 + r] = o[j];
}

// ---------------------------------------------------------------------------
extern "C" void kernel_launch(void* const* d_in, const int* in_sizes, int n_in,
                              void* d_out, int out_size, void* d_ws, size_t ws_size,
                              hipStream_t stream)
{
    const float* x  = (const float*)d_in[0];
    const float* wq = (const float*)d_in[1];
    const float* bq = (const float*)d_in[2];
    const float* wk = (const float*)d_in[3];
    const float* bk = (const float*)d_in[4];
    const float* wv = (const float*)d_in[5];
    const float* bv = (const float*)d_in[6];
    const float* wo = (const float*)d_in[7];
    float* out = (float*)d_out;

    // workspace layout (bytes)
    char* base = (char*)d_ws;
    half4*    qhi    = (half4*)(base + 0);          //  393216
    half4*    qlo    = (half4*)(base + 393216);
    half4*    khi    = (half4*)(base + 786432);
    half4*    klo    = (half4*)(base + 1179648);
    _Float16* vT     = (_Float16*)(base + 1572864); //  491520 (8h x 5 planes)
    _Float16* attpad = (_Float16*)(base + 2064384); //  416000 -> 2480384

    hipLaunchKernelGGL(qkv_mfma_kernel, dim3(1152), dim3(384), 0, stream,
                       x, wq, bq, wk, bk, wv, bv, qhi, qlo, khi, klo, vT);

    hipLaunchKernelGGL(attn_mfma_kernel, dim3(16 * 48), dim3(512), 0, stream,
                       qhi, qlo, khi, klo, vT, attpad);

    hipLaunchKernelGGL(out_mfma_kernel, dim3(4 * 384), dim3(192), 0, stream,
                       attpad, wo, out);
}